// Round 1
// baseline (579.274 us; speedup 1.0000x reference)
//
#include <hip/hip_runtime.h>

#define BB 4
#define S 128
#define SS (S*S)
#define BSS (BB*SS)
#define JSPLIT 4
#define ISPLIT 2

__device__ __forceinline__ int off3(int b, int i, int j) { return (b * S + i) * S + j; }
__device__ __forceinline__ int off4(int b, int i, int j, int k) { return ((b * S + i) * S + j) * S + k; }

// ---------------------------------------------------------------------------
// Per-iteration: q = sigmoid(base), plus transposed copies for contiguous access.
// ws layout (floats): qb[0], qe[1], qs[2], qbT[3], qeT[4], qsT[5] each BSS.
// ---------------------------------------------------------------------------
__global__ __launch_bounds__(128) void k_sigmoid(const float* __restrict__ base,
                                                 float* __restrict__ ws) {
    int bi = blockIdx.x;
    int b = bi >> 7, i = bi & (S - 1);
    int j = threadIdx.x;
#pragma unroll
    for (int t = 0; t < 3; ++t) {
        float x = base[t * BSS + off3(b, i, j)];
        float q = 1.0f / (1.0f + expf(-x));
        ws[t * BSS + off3(b, i, j)] = q;
        ws[(3 + t) * BSS + off3(b, j, i)] = q;
    }
}

// ---------------------------------------------------------------------------
// 7 natural-layout tensors. wg = (jchunk, I, b). lanes cover k via float2.
// accB[j] = sum_k qe[I,k]*be*wm + qb[I,k]*bb*m2o + qbT[j,k]*cop_b*m2o
// accE[j] = sum_k qb[I,k]*eb*wm(I,k,j) + qe[I,k]*ee*m2o + qeT[j,k]*cop_e*m2o
// accS[j] = sum_k qs[I,k]*split*span(I,j,k)
//   wm(i,j,k)  = e[i,j]&e[i,k]&(i!=k)
//   m2o        = wm & (j!=k)
//   wm(i,k,j)  = e[i,k]&e[i,j]&(i!=j)
//   span(i,j,k)= chart[i-1,j]&(max(i,j)!=k)&c0[j]&c0[k]
// ---------------------------------------------------------------------------
__global__ __launch_bounds__(256) void k_sib(
    const float* __restrict__ be, const float* __restrict__ bb,
    const float* __restrict__ cb, const float* __restrict__ eb,
    const float* __restrict__ ee, const float* __restrict__ ce,
    const float* __restrict__ sp, const int* __restrict__ edge,
    const int* __restrict__ chart, const float* __restrict__ ws,
    float* __restrict__ base) {
    const int b = blockIdx.z, I = blockIdx.y;
    const int jbase = blockIdx.x * (S / JSPLIT);
    const int t = threadIdx.x, w = t >> 6, l = t & 63;
    const int k0 = 2 * l, k1 = 2 * l + 1;

    const float* qb = ws;
    const float* qe = ws + BSS;
    const float* qs = ws + 2 * BSS;
    const float* qbT = ws + 3 * BSS;
    const float* qeT = ws + 4 * BSS;

    const int2 e_k = *(const int2*)&edge[off3(b, I, k0)];
    const float2 qe_i = *(const float2*)&qe[off3(b, I, k0)];
    const float2 qb_i = *(const float2*)&qb[off3(b, I, k0)];
    const float2 qs_i = *(const float2*)&qs[off3(b, I, k0)];
    const int2 c0k = *(const int2*)&chart[off3(b, 0, k0)];
    const int Iprev = (I + S - 1) & (S - 1);
    const bool ek0 = e_k.x != 0, ek1 = e_k.y != 0;
    const bool c0k0 = c0k.x != 0, c0k1 = c0k.y != 0;

    for (int jj = 0; jj < (S / JSPLIT) / 4; ++jj) {
        const int j = jbase + w + 4 * jj;
        const bool e_ij = edge[off3(b, I, j)] != 0;
        const bool chIj = chart[off3(b, Iprev, j)] != 0;
        const bool c0j = chart[off3(b, 0, j)] != 0;
        const float2 qbT_j = *(const float2*)&qbT[off3(b, j, k0)];
        const float2 qeT_j = *(const float2*)&qeT[off3(b, j, k0)];

        const int b4 = off4(b, I, j, 0);
        const float2 v_be = *(const float2*)&be[b4 + k0];
        const float2 v_bb = *(const float2*)&bb[b4 + k0];
        const float2 v_cb = *(const float2*)&cb[b4 + k0];
        const float2 v_eb = *(const float2*)&eb[b4 + k0];
        const float2 v_ee = *(const float2*)&ee[b4 + k0];
        const float2 v_ce = *(const float2*)&ce[b4 + k0];
        const float2 v_sp = *(const float2*)&sp[b4 + k0];

        const int mx = I > j ? I : j;
        const bool wmk = e_ij && (I != j);  // & e[I,k] per-half below

        // half k0
        bool wm0 = e_ij && ek0 && (I != k0);
        bool m20 = wm0 && (j != k0);
        bool wk0 = ek0 && wmk;
        bool sp0 = chIj && (mx != k0) && c0j && c0k0;
        float accB = (wm0 ? qe_i.x : 0.f) * v_be.x + (m20 ? qb_i.x : 0.f) * v_bb.x +
                     (m20 ? qbT_j.x : 0.f) * v_cb.x;
        float accE = (wk0 ? qb_i.x : 0.f) * v_eb.x + (m20 ? qe_i.x : 0.f) * v_ee.x +
                     (m20 ? qeT_j.x : 0.f) * v_ce.x;
        float accS = (sp0 ? qs_i.x : 0.f) * v_sp.x;
        // half k1
        bool wm1 = e_ij && ek1 && (I != k1);
        bool m21 = wm1 && (j != k1);
        bool wk1 = ek1 && wmk;
        bool sp1 = chIj && (mx != k1) && c0j && c0k1;
        accB += (wm1 ? qe_i.y : 0.f) * v_be.y + (m21 ? qb_i.y : 0.f) * v_bb.y +
                (m21 ? qbT_j.y : 0.f) * v_cb.y;
        accE += (wk1 ? qb_i.y : 0.f) * v_eb.y + (m21 ? qe_i.y : 0.f) * v_ee.y +
                (m21 ? qeT_j.y : 0.f) * v_ce.y;
        accS += (sp1 ? qs_i.y : 0.f) * v_sp.y;

#pragma unroll
        for (int o = 32; o > 0; o >>= 1) {
            accB += __shfl_xor(accB, o);
            accE += __shfl_xor(accE, o);
            accS += __shfl_xor(accS, o);
        }
        if (l == 0) {
            atomicAdd(&base[0 * BSS + off3(b, I, j)], accB);
            atomicAdd(&base[1 * BSS + off3(b, I, j)], accE);
            atomicAdd(&base[2 * BSS + off3(b, I, j)], accS);
        }
    }
}

// ---------------------------------------------------------------------------
// s_grd_b / s_grd_e: single pass serves both their edge (natural) and span
// (transposed) consumers. wg = (isplit, J, b); lanes cover K (float2); loop I.
//  edge_b: base_b[b,I,J] += sum_K qs[J,K]*gb[I,J,K]*nc(I,J,K)
//  edge_e: base_e[b,I,J] += sum_K qsT[J,K]*ge[I,J,K]*nc(I,K,J)
//  span_b: base_s[b,J,K] += sum_I qbT[J,I]*gb[I,J,K]*outside(J,K,I)
//  span_e: base_s[b,K,J] += sum_I qeT[J,I]*ge[I,J,K]*outside(K,J,I)
//   nc(i,j,k) = e[i,j]&e[i,k]&(i!=k)&(j<=k)&(j>=i||k<=i)
//   outside(i,j,k) = !((i<=k)&&(j>=k)) & chart[i-1,j]&(max(i,j)!=k)&c0[j]&c0[k]
// ---------------------------------------------------------------------------
__global__ __launch_bounds__(256) void k_grd(
    const float* __restrict__ gb, const float* __restrict__ ge,
    const int* __restrict__ edge, const int* __restrict__ chart,
    const float* __restrict__ ws, float* __restrict__ base) {
    const int b = blockIdx.z, J = blockIdx.y;
    const int is = blockIdx.x;
    const int t = threadIdx.x, h = t >> 6, l = t & 63;
    const int K0 = 2 * l, K1 = 2 * l + 1;

    const float* qs = ws + 2 * BSS;
    const float* qbT = ws + 3 * BSS;
    const float* qeT = ws + 4 * BSS;
    const float* qsT = ws + 5 * BSS;

    const float2 qs_J = *(const float2*)&qs[off3(b, J, K0)];
    const float2 qsT_J = *(const float2*)&qsT[off3(b, J, K0)];
    const int2 c0Kv = *(const int2*)&chart[off3(b, 0, K0)];
    const bool c0K0 = c0Kv.x != 0, c0K1 = c0Kv.y != 0;
    const bool c0J = chart[off3(b, 0, J)] != 0;
    const int Jprev = (J + S - 1) & (S - 1);
    const int2 chJKv = *(const int2*)&chart[off3(b, Jprev, K0)];
    const bool chJK0 = chJKv.x != 0, chJK1 = chJKv.y != 0;
    const bool chKJ0 = chart[off3(b, (K0 + S - 1) & (S - 1), J)] != 0;
    const bool chKJ1 = chart[off3(b, K0, J)] != 0;  // (K1-1) == K0
    const int mxJ0 = J > K0 ? J : K0;
    const int mxJ1 = J > K1 ? J : K1;

    float rs_b0 = 0.f, rs_b1 = 0.f, rs_e0 = 0.f, rs_e1 = 0.f;

    for (int ib = is * (32 / ISPLIT); ib < (is + 1) * (32 / ISPLIT); ++ib) {
        const int I = 4 * ib + h;  // all 64 lanes of a wave share I
        const float2 v_b = *(const float2*)&gb[off4(b, I, J, K0)];
        const float2 v_e = *(const float2*)&ge[off4(b, I, J, K0)];
        const int2 e_IKv = *(const int2*)&edge[off3(b, I, K0)];
        const bool eIK0 = e_IKv.x != 0, eIK1 = e_IKv.y != 0;
        const bool eIJ = edge[off3(b, I, J)] != 0;
        const bool c0I = chart[off3(b, 0, I)] != 0;
        const float qbT_JI = qbT[off3(b, J, I)];
        const float qeT_JI = qeT[off3(b, J, I)];

        // edge terms -> reduce over K lanes
        bool nc1_0 = eIJ && eIK0 && (I != K0) && (J <= K0) && (J >= I || K0 <= I);
        bool nc1_1 = eIJ && eIK1 && (I != K1) && (J <= K1) && (J >= I || K1 <= I);
        bool nc2_0 = eIK0 && eIJ && (I != J) && (K0 <= J) && (K0 >= I || J <= I);
        bool nc2_1 = eIK1 && eIJ && (I != J) && (K1 <= J) && (K1 >= I || J <= I);
        float pb = (nc1_0 ? qs_J.x : 0.f) * v_b.x + (nc1_1 ? qs_J.y : 0.f) * v_b.y;
        float pe = (nc2_0 ? qsT_J.x : 0.f) * v_e.x + (nc2_1 ? qsT_J.y : 0.f) * v_e.y;

        // span terms -> accumulate over I in registers
        bool o1_0 = !((J <= I) && (K0 >= I)) && chJK0 && (mxJ0 != I) && c0K0 && c0I;
        bool o1_1 = !((J <= I) && (K1 >= I)) && chJK1 && (mxJ1 != I) && c0K1 && c0I;
        bool o2_0 = !((K0 <= I) && (J >= I)) && chKJ0 && (mxJ0 != I) && c0J && c0I;
        bool o2_1 = !((K1 <= I) && (J >= I)) && chKJ1 && (mxJ1 != I) && c0J && c0I;
        rs_b0 += (o1_0 ? qbT_JI : 0.f) * v_b.x;
        rs_b1 += (o1_1 ? qbT_JI : 0.f) * v_b.y;
        rs_e0 += (o2_0 ? qeT_JI : 0.f) * v_e.x;
        rs_e1 += (o2_1 ? qeT_JI : 0.f) * v_e.y;

#pragma unroll
        for (int o = 32; o > 0; o >>= 1) {
            pb += __shfl_xor(pb, o);
            pe += __shfl_xor(pe, o);
        }
        if (l == 0) {
            atomicAdd(&base[0 * BSS + off3(b, I, J)], pb);
            atomicAdd(&base[1 * BSS + off3(b, I, J)], pe);
        }
    }
    atomicAdd(&base[2 * BSS + off3(b, J, K0)], rs_b0);
    atomicAdd(&base[2 * BSS + off3(b, J, K1)], rs_b1);
    atomicAdd(&base[2 * BSS + off3(b, K0, J)], rs_e0);
    atomicAdd(&base[2 * BSS + off3(b, K1, J)], rs_e1);
}

extern "C" void kernel_launch(void* const* d_in, const int* in_sizes, int n_in,
                              void* d_out, int out_size, void* d_ws, size_t ws_size,
                              hipStream_t stream) {
    (void)in_sizes; (void)n_in; (void)out_size; (void)ws_size;
    const float* s_const = (const float*)d_in[0];
    const float* s_arg_begin = (const float*)d_in[1];
    const float* s_arg_end = (const float*)d_in[2];
    const float* be = (const float*)d_in[3];
    const float* eb = (const float*)d_in[4];
    const float* bb = (const float*)d_in[5];
    const float* ee = (const float*)d_in[6];
    const float* cb = (const float*)d_in[7];
    const float* ce = (const float*)d_in[8];
    const float* gb = (const float*)d_in[9];
    const float* ge = (const float*)d_in[10];
    const float* sp = (const float*)d_in[11];
    const int* edge = (const int*)d_in[12];   // arg_begin_mask (bool -> int32 assumed)
    const int* chart = (const int*)d_in[13];  // chart_mask
    float* base = (float*)d_out;
    float* ws = (float*)d_ws;

    // base_b = s_arg_begin, base_e = s_arg_end, base_s = s_const (output order)
    hipMemcpyAsync(base, s_arg_begin, BSS * sizeof(float), hipMemcpyDeviceToDevice, stream);
    hipMemcpyAsync(base + BSS, s_arg_end, BSS * sizeof(float), hipMemcpyDeviceToDevice, stream);
    hipMemcpyAsync(base + 2 * BSS, s_const, BSS * sizeof(float), hipMemcpyDeviceToDevice, stream);

    for (int it = 0; it < 3; ++it) {
        k_sigmoid<<<dim3(BB * S), dim3(S), 0, stream>>>(base, ws);
        k_sib<<<dim3(JSPLIT, S, BB), dim3(256), 0, stream>>>(be, bb, cb, eb, ee, ce, sp,
                                                             edge, chart, ws, base);
        k_grd<<<dim3(ISPLIT, S, BB), dim3(256), 0, stream>>>(gb, ge, edge, chart, ws, base);
    }
}